// Round 6
// baseline (778.357 us; speedup 1.0000x reference)
//
#include <hip/hip_runtime.h>
#include <hip/hip_bf16.h>
#include <cstdint>
#include <cstddef>

#define B_ 8
#define S_ 1024
#define H_ 16
#define HS_ 64
#define D_ 1024

typedef __bf16 bf16x8 __attribute__((ext_vector_type(8)));
typedef float f32x4 __attribute__((ext_vector_type(4)));
typedef unsigned short u16x8 __attribute__((ext_vector_type(8)));

__device__ inline unsigned short f2bf(float f) {
    return __builtin_bit_cast(unsigned short, (__bf16)f);
}
__device__ inline float bf2f(unsigned short u) {
    unsigned int v = ((unsigned int)u) << 16;
    return __builtin_bit_cast(float, v);
}
__device__ inline f32x4 mfma16(bf16x8 a, bf16x8 b, f32x4 c) {
    return __builtin_amdgcn_mfma_f32_16x16x32_bf16(a, b, c, 0, 0, 0);
}
__device__ inline void gload_lds16(const void* g, void* l) {
    auto gp = (const __attribute__((address_space(1))) unsigned int*)(g);
    auto lp = (__attribute__((address_space(3))) unsigned int*)(l);
    __builtin_amdgcn_global_load_lds(gp, lp, 16, 0, 0);
}

// ---------------- prep: x fp32->bf16 (blocks 0..8191) + weight transpose (8192..9215) ----
__global__ __launch_bounds__(256) void prep_k(
    const float* __restrict__ x, unsigned short* __restrict__ xb,
    const float* __restrict__ w0, const float* __restrict__ w1,
    const float* __restrict__ w2, const float* __restrict__ w3,
    unsigned short* __restrict__ o0, unsigned short* __restrict__ o1,
    unsigned short* __restrict__ o2, unsigned short* __restrict__ o3) {
    __shared__ float tile[64][65];
    const int bid = blockIdx.x;
    if (bid < 8192) {
        int i = bid * 256 + threadIdx.x;   // 1 float4 per thread
        float4 v = ((const float4*)x)[i];
        ushort4 o;
        o.x = f2bf(v.x); o.y = f2bf(v.y); o.z = f2bf(v.z); o.w = f2bf(v.w);
        ((ushort4*)xb)[i] = o;
        return;
    }
    const int idx = bid - 8192;            // 0..1023
    const int z = idx >> 8, rem = idx & 255;
    const float* src; unsigned short* dst;
    switch (z) {
        case 0: src = w0; dst = o0; break;
        case 1: src = w1; dst = o1; break;
        case 2: src = w2; dst = o2; break;
        default: src = w3; dst = o3; break;
    }
    const int n0 = (rem & 15) * 64, k0 = (rem >> 4) * 64;
    const int tx = threadIdx.x & 63, ty = threadIdx.x >> 6;
#pragma unroll
    for (int i = 0; i < 16; i++)
        tile[ty + 4 * i][tx] = src[(size_t)(k0 + ty + 4 * i) * D_ + n0 + tx];
    __syncthreads();
#pragma unroll
    for (int i = 0; i < 16; i++)
        dst[(size_t)(n0 + ty + 4 * i) * D_ + k0 + tx] = f2bf(tile[tx][ty + 4 * i]);
}

// ---------------- GEMM: C[M=8192][N=1024] = A[M][K=1024] @ BT[N][K]^T + bias ----------------
// MODE 0: out bf16 [B][H][S][HS]   (Q, K)
// MODE 1: out bf16 [B][H][HS][S]   (V transposed)
// MODE 2: out bf16 [M][N]          (out-projection; bf16 ok — feeds residual+LN where x fp32 dominates)
// 1-D grid of 512 blocks, XCD-swizzled: each XCD owns 8 consecutive m-panels
// (A 8x256KB + B 2MB = 4MB = one XCD L2).
template <int MODE>
__global__ __launch_bounds__(256, 2) void gemm_k(const unsigned short* __restrict__ A,
                                                 const unsigned short* __restrict__ BT,
                                                 const float* __restrict__ bias,
                                                 void* __restrict__ outp) {
    __shared__ __attribute__((aligned(128))) char smem[65536];  // 2 bufs x (A 16KB + B 16KB)
    const int t = threadIdx.x;
    const int l = t & 63;
    const int w = t >> 6;
    const int bid = blockIdx.x;                      // 0..511, 512 % 8 == 0 -> bijective
    const int tile = (bid & 7) * 64 + (bid >> 3);    // XCD-contiguous chunks
    const int m0 = (tile >> 3) * 128;
    const int n0 = (tile & 7) * 128;
    const int wr = w >> 1, wc = w & 1;
    const int l15 = l & 15, l4 = l >> 4;
    const int lrow8 = l >> 3;
    const int lcolb = ((l & 7) * 16) ^ (lrow8 << 4);  // pre-swizzled source column (bytes)

    f32x4 acc[4][4];
#pragma unroll
    for (int m = 0; m < 4; m++)
#pragma unroll
        for (int n = 0; n < 4; n++) acc[m][n] = (f32x4){0.f, 0.f, 0.f, 0.f};

    auto stage = [&](int buf, int kt) {
        char* base = smem + buf * 32768;
#pragma unroll
        for (int q = 0; q < 4; q++) {
            int chunk = w * 4 + q;
            int row = chunk * 8 + lrow8;
            const char* ga = (const char*)A + ((size_t)(m0 + row) * D_ + kt * 64) * 2 + lcolb;
            gload_lds16(ga, base + chunk * 1024);
            const char* gb = (const char*)BT + ((size_t)(n0 + row) * D_ + kt * 64) * 2 + lcolb;
            gload_lds16(gb, base + 16384 + chunk * 1024);
        }
    };
    auto compute = [&](int buf) {
        const char* As = smem + buf * 32768;
        const char* Bs = As + 16384;
#pragma unroll
        for (int kk = 0; kk < 2; kk++) {
            const int cb = (kk * 64 + l4 * 16) ^ ((l & 7) << 4);  // swizzled read col (bytes)
            bf16x8 av[4], bv[4];
#pragma unroll
            for (int m = 0; m < 4; m++)
                av[m] = *(const bf16x8*)(As + (wr * 64 + m * 16 + l15) * 128 + cb);
#pragma unroll
            for (int n = 0; n < 4; n++)
                bv[n] = *(const bf16x8*)(Bs + (wc * 64 + n * 16 + l15) * 128 + cb);
#pragma unroll
            for (int m = 0; m < 4; m++)
#pragma unroll
                for (int n = 0; n < 4; n++) acc[m][n] = mfma16(av[m], bv[n], acc[m][n]);
        }
    };

    stage(0, 0);
    __syncthreads();
    int buf = 0;
    for (int kt = 0; kt < 16; ++kt) {
        if (kt < 15) stage(buf ^ 1, kt + 1);
        compute(buf);
        __syncthreads();
        buf ^= 1;
    }

#pragma unroll
    for (int n = 0; n < 4; n++) {
        const int c = n0 + wc * 64 + n * 16 + l15;
        const float bc = bias[c];
#pragma unroll
        for (int m = 0; m < 4; m++) {
            const int rbase = m0 + wr * 64 + m * 16 + l4 * 4;
            if (MODE == 0) {
#pragma unroll
                for (int i = 0; i < 4; i++) {
                    int r = rbase + i;
                    ((unsigned short*)outp)[(((size_t)(r >> 10) * H_ + (c >> 6)) * S_ + (r & 1023)) * HS_ + (c & 63)] =
                        f2bf(acc[m][n][i] + bc);
                }
            } else if (MODE == 1) {
                ushort4 pk;
                pk.x = f2bf(acc[m][n][0] + bc);
                pk.y = f2bf(acc[m][n][1] + bc);
                pk.z = f2bf(acc[m][n][2] + bc);
                pk.w = f2bf(acc[m][n][3] + bc);
                int bb = rbase >> 10, s0 = rbase & 1023;
                *(ushort4*)((unsigned short*)outp +
                            (((size_t)bb * H_ + (c >> 6)) * HS_ + (c & 63)) * S_ + s0) = pk;
            } else {
#pragma unroll
                for (int i = 0; i < 4; i++) {
                    int r = rbase + i;
                    ((unsigned short*)outp)[(size_t)r * D_ + c] = f2bf(acc[m][n][i] + bc);
                }
            }
        }
    }
}

// ---------------- fused attention ----------------
// 1-D grid 4096 (XCD-swizzled so 16 consecutive (b,h) share one XCD L2), 4 waves.
// LDS: P[32 rows][2048 B, XOR-swizzled] | KV double buffer 2 x [64][128B, XOR-swizzled]
// Q lives in registers. K/V staged via global_load_lds with pre-swizzled global source.
__global__ __launch_bounds__(256, 2) void attn_k(
    const unsigned short* __restrict__ qb, const unsigned short* __restrict__ kb,
    const unsigned short* __restrict__ vT, const int* __restrict__ mask,
    unsigned short* __restrict__ ctx, float* __restrict__ attn_out) {
    __shared__ __attribute__((aligned(128))) char smem[81920];
    char* Pl = smem;                 // 65536 B
    char* KV0 = smem + 65536;        // 8192 B
    char* KV1 = smem + 73728;        // 8192 B

    const int t = threadIdx.x, l = t & 63, w = t >> 6;
    const unsigned bid = blockIdx.x;               // 4096 % 8 == 0 -> bijective
    const unsigned tile = (bid & 7) * 512 + (bid >> 3);
    const int qt = tile & 31;
    const int bh = tile >> 5;
    const int b = bh >> 4, h = bh & 15;
    const int q0 = qt * 32;
    const int l15 = l & 15, l4 = l >> 4;
    const int lrow8 = l >> 3;
    const int lcolb = ((l & 7) << 4) ^ (lrow8 << 4);   // pre-swizzled source col (bytes)
    const int swz = (l & 7) << 4;                      // read-side XOR ((row&7)<<4, row%8==l%8)

    const size_t kbase = (size_t)bh * S_;

    auto stageK = [&](char* dst, int kt) {
#pragma unroll
        for (int q = 0; q < 2; q++) {
            int chunk = w * 2 + q;
            int row = chunk * 8 + lrow8;
            const char* g = (const char*)(kb + (kbase + kt * 64 + row) * HS_) + lcolb;
            gload_lds16(g, dst + chunk * 1024);
        }
    };
    auto stageV = [&](char* dst, int vt) {
#pragma unroll
        for (int q = 0; q < 2; q++) {
            int chunk = w * 2 + q;
            int row = chunk * 8 + lrow8;   // hs index
            const char* g = (const char*)(vT + ((size_t)bh * HS_ + row) * S_ + vt * 64) + lcolb;
            gload_lds16(g, dst + chunk * 1024);
        }
    };

    stageK(KV0, 0);   // async; lands before first barrier's implicit vmcnt(0)

    // Q tile -> registers: lane needs Q[q0 + half*16 + l15][kk*32 + l4*8 .. +7]
    bf16x8 qf[2][2];
#pragma unroll
    for (int half = 0; half < 2; half++)
#pragma unroll
        for (int kk = 0; kk < 2; kk++)
            qf[half][kk] = __builtin_bit_cast(bf16x8,
                *(const u16x8*)(qb + (kbase + q0 + half * 16 + l15) * HS_ + kk * 32 + l4 * 8));

    // hoist mask bias out of the K-loop: 16 values in registers
    float biasarr[16];
#pragma unroll
    for (int kt = 0; kt < 16; kt++)
        biasarr[kt] = -10000.f * (float)mask[b * S_ + kt * 64 + w * 16 + l15];

    __syncthreads();
    // ---- QK^T ----
    char* cur = KV0; char* nxt = KV1;
    for (int kt = 0; kt < 16; ++kt) {
        if (kt < 15) stageK(nxt, kt + 1);
        const int nb = kt * 64 + w * 16;
        const float biasv = biasarr[kt];
        f32x4 a0 = {0.f, 0.f, 0.f, 0.f}, a1 = {0.f, 0.f, 0.f, 0.f};
        __builtin_amdgcn_s_setprio(1);
#pragma unroll
        for (int kk = 0; kk < 2; kk++) {
            bf16x8 kf = *(const bf16x8*)(cur + (w * 16 + l15) * 128 + ((kk * 64 + l4 * 16) ^ swz));
            a0 = mfma16(qf[0][kk], kf, a0);
            a1 = mfma16(qf[1][kk], kf, a1);
        }
        __builtin_amdgcn_s_setprio(0);
        const int cb = (nb + l15) * 2;
#pragma unroll
        for (int i = 0; i < 4; i++) {
            int r0 = l4 * 4 + i;                    // rows r0 and 16+r0 share (row&7)
            int rs = (r0 & 7) << 4;
            *(unsigned short*)(Pl + r0 * 2048 + (cb ^ rs)) = f2bf(a0[i] * 0.125f + biasv);
            *(unsigned short*)(Pl + (16 + r0) * 2048 + (cb ^ rs)) = f2bf(a1[i] * 0.125f + biasv);
        }
        __syncthreads();
        char* tmp = cur; cur = nxt; nxt = tmp;
    }

    stageV(KV0, 0);   // prefetch V tile 0 under the whole softmax phase (KV0 is free here)

    // ---- softmax: one wave per row; float4 I/O ----
    for (int j = 0; j < 8; j++) {
        int r = w * 8 + j;
        int rs = (r & 7) << 4;
        char* prow = Pl + r * 2048;
        float v[16];
        float mx = -3.0e38f;
#pragma unroll
        for (int i = 0; i < 4; i++) {
            uint2 u = *(const uint2*)(prow + ((l * 8 + i * 512) ^ rs));
            float f0 = bf2f((unsigned short)(u.x & 0xffffu));
            float f1 = bf2f((unsigned short)(u.x >> 16));
            float f2 = bf2f((unsigned short)(u.y & 0xffffu));
            float f3 = bf2f((unsigned short)(u.y >> 16));
            v[4 * i] = f0; v[4 * i + 1] = f1; v[4 * i + 2] = f2; v[4 * i + 3] = f3;
            mx = fmaxf(mx, fmaxf(fmaxf(f0, f1), fmaxf(f2, f3)));
        }
#pragma unroll
        for (int off = 32; off >= 1; off >>= 1) mx = fmaxf(mx, __shfl_xor(mx, off));
        float sum = 0.f;
#pragma unroll
        for (int i = 0; i < 16; i++) { v[i] = __expf(v[i] - mx); sum += v[i]; }
#pragma unroll
        for (int off = 32; off >= 1; off >>= 1) sum += __shfl_xor(sum, off);
        float inv = 1.f / sum;
        float* gout = attn_out + ((size_t)bh * S_ + q0 + r) * S_;
#pragma unroll
        for (int i = 0; i < 4; i++) {
            float f0 = v[4 * i] * inv, f1 = v[4 * i + 1] * inv;
            float f2 = v[4 * i + 2] * inv, f3 = v[4 * i + 3] * inv;
            f32x4 o = {f0, f1, f2, f3};
            __builtin_nontemporal_store(o, (f32x4*)(gout + 4 * l + 256 * i));
            uint2 pk;
            pk.x = (unsigned int)f2bf(f0) | ((unsigned int)f2bf(f1) << 16);
            pk.y = (unsigned int)f2bf(f2) | ((unsigned int)f2bf(f3) << 16);
            *(uint2*)(prow + ((l * 8 + i * 512) ^ rs)) = pk;
        }
    }
    __syncthreads();   // drains V tile 0; P write-back visible

    // ---- PV ----
    cur = KV0; nxt = KV1;
    f32x4 c0 = {0.f, 0.f, 0.f, 0.f}, c1 = {0.f, 0.f, 0.f, 0.f};
    for (int vt = 0; vt < 16; ++vt) {
        if (vt < 15) stageV(nxt, vt + 1);
        __builtin_amdgcn_s_setprio(1);
#pragma unroll
        for (int kk = 0; kk < 2; kk++) {
            bf16x8 vf = *(const bf16x8*)(cur + (w * 16 + l15) * 128 + ((kk * 64 + l4 * 16) ^ swz));
            bf16x8 p0 = *(const bf16x8*)(Pl + l15 * 2048 + ((vt * 128 + kk * 64 + l4 * 16) ^ swz));
            bf16x8 p1 = *(const bf16x8*)(Pl + (16 + l15) * 2048 + ((vt * 128 + kk * 64 + l4 * 16) ^ swz));
            c0 = mfma16(p0, vf, c0);
            c1 = mfma16(p1, vf, c1);
        }
        __builtin_amdgcn_s_setprio(0);
        __syncthreads();
        char* tmp = cur; cur = nxt; nxt = tmp;
    }
#pragma unroll
    for (int i = 0; i < 4; i++) {
        int sq = l4 * 4 + i;
        int cidx = h * HS_ + w * 16 + l15;
        ctx[((size_t)(b * S_ + q0 + sq)) * D_ + cidx] = f2bf(c0[i]);
        ctx[((size_t)(b * S_ + q0 + 16 + sq)) * D_ + cidx] = f2bf(c1[i]);
    }
}

// ---------------- residual + LayerNorm (proj is bf16) ----------------
__global__ __launch_bounds__(256) void ln_k(const float* __restrict__ x,
                                            const unsigned short* __restrict__ proj,
                                            const float* __restrict__ gamma,
                                            const float* __restrict__ beta,
                                            float* __restrict__ out) {
    __shared__ float red[8];
    const int r = blockIdx.x, t = threadIdx.x, l = t & 63, w = t >> 6;
    const size_t base = (size_t)r * D_ + t * 4;
    float4 xv = *(const float4*)(x + base);
    ushort4 pb = *(const ushort4*)(proj + base);
    float a0 = xv.x + bf2f(pb.x), a1 = xv.y + bf2f(pb.y);
    float a2 = xv.z + bf2f(pb.z), a3 = xv.w + bf2f(pb.w);
    float s = a0 + a1 + a2 + a3;
#pragma unroll
    for (int off = 32; off >= 1; off >>= 1) s += __shfl_xor(s, off);
    if (l == 0) red[w] = s;
    __syncthreads();
    float mean = (red[0] + red[1] + red[2] + red[3]) * (1.f / 1024.f);
    float d0 = a0 - mean, d1 = a1 - mean, d2 = a2 - mean, d3 = a3 - mean;
    float sq = d0 * d0 + d1 * d1 + d2 * d2 + d3 * d3;
#pragma unroll
    for (int off = 32; off >= 1; off >>= 1) sq += __shfl_xor(sq, off);
    if (l == 0) red[4 + w] = sq;
    __syncthreads();
    float var = (red[4] + red[5] + red[6] + red[7]) * (1.f / 1024.f);
    float rs = rsqrtf(var + 1e-6f);
    float4 gv = *(const float4*)(gamma + t * 4);
    float4 bv = *(const float4*)(beta + t * 4);
    float4 o;
    o.x = d0 * rs * gv.x + bv.x;
    o.y = d1 * rs * gv.y + bv.y;
    o.z = d2 * rs * gv.z + bv.z;
    o.w = d3 * rs * gv.w + bv.w;
    *(float4*)(out + base) = o;
}

extern "C" void kernel_launch(void* const* d_in, const int* in_sizes, int n_in,
                              void* d_out, int out_size, void* d_ws, size_t ws_size,
                              hipStream_t stream) {
    const float* x     = (const float*)d_in[0];
    const int*   mask  = (const int*)d_in[1];
    const float* wq    = (const float*)d_in[2];
    const float* bq    = (const float*)d_in[3];
    const float* wk    = (const float*)d_in[4];
    const float* bk    = (const float*)d_in[5];
    const float* wv    = (const float*)d_in[6];
    const float* bv    = (const float*)d_in[7];
    const float* wo    = (const float*)d_in[8];
    const float* bo    = (const float*)d_in[9];
    const float* gamma = (const float*)d_in[10];
    const float* beta  = (const float*)d_in[11];

    // Compact workspace (72 MB) via lifetime aliasing:
    //   [0,16M):    XBF (phases 1-3)  then CTX (attn output, phase 4+)
    //   [16M,24M):  transposed bf16 weights
    //   [24M,56M):  QB,KB (phases 3-4) then PROJ bf16 (phase 5+)
    //   [56M,72M):  VT
    char* ws = (char*)d_ws;
    unsigned short* XBF = (unsigned short*)(ws + 0);
    unsigned short* CTX = (unsigned short*)(ws + 0);
    unsigned short* WTQ = (unsigned short*)(ws + 16777216);
    unsigned short* WTK = (unsigned short*)(ws + 18874368);
    unsigned short* WTV = (unsigned short*)(ws + 20971520);
    unsigned short* WTO = (unsigned short*)(ws + 23068672);
    unsigned short* QB  = (unsigned short*)(ws + 25165824);
    unsigned short* KB  = (unsigned short*)(ws + 41943040);
    unsigned short* PROJ = (unsigned short*)(ws + 25165824);
    unsigned short* VT  = (unsigned short*)(ws + 58720256);

    float* out  = (float*)d_out;
    float* attn = out + (size_t)B_ * S_ * D_;

    prep_k<<<9216, 256, 0, stream>>>(x, XBF, wq, wk, wv, wo, WTQ, WTK, WTV, WTO);
    gemm_k<0><<<512, 256, 0, stream>>>(XBF, WTQ, bq, QB);
    gemm_k<0><<<512, 256, 0, stream>>>(XBF, WTK, bk, KB);
    gemm_k<1><<<512, 256, 0, stream>>>(XBF, WTV, bv, VT);
    attn_k<<<4096, 256, 0, stream>>>(QB, KB, VT, mask, CTX, attn);
    gemm_k<2><<<512, 256, 0, stream>>>(CTX, WTO, bo, PROJ);
    ln_k<<<8192, 256, 0, stream>>>(x, PROJ, gamma, beta, out);
}